// Round 1
// baseline (2529.262 us; speedup 1.0000x reference)
//
#include <hip/hip_runtime.h>
#include <math.h>

#if __has_builtin(__builtin_amdgcn_exp2f)
#define EXP2F(x) __builtin_amdgcn_exp2f(x)
#else
#define EXP2F(x) exp2f(x)
#endif

#if __has_builtin(__builtin_amdgcn_logf)
#define LOG2F(x) __builtin_amdgcn_logf(x)
#else
#define LOG2F(x) log2f(x)
#endif

#if __has_builtin(__builtin_amdgcn_rcpf)
#define RCPF(x) __builtin_amdgcn_rcpf(x)
#else
#define RCPF(x) (1.0f / (x))
#endif

#define L2E 1.44269504088896340736f
#define LN2 0.69314718055994530942f

// Problem constants
constexpr int V = 32000;
constexpr int H = 8;
constexpr int E = 32;
constexpr int T = 1024;
constexpr int B = 8;
constexpr int TB = T * B;        // 8192 rows
constexpr int V4 = V / 4;        // 8000 float4 per row

// ---------------------------------------------------------------------------
// Kernel A: pre[dir][t][b][h] = emb[x[t,b]] @ Wx + bx[h] + bh[h]
// Fully parallel: 2*T*B*H = 131072 elements.
// ---------------------------------------------------------------------------
__global__ __launch_bounds__(256) void proj_kernel(
    const int* __restrict__ x, const float* __restrict__ emb,
    const float* __restrict__ Wx1, const float* __restrict__ bx1,
    const float* __restrict__ bh1,
    const float* __restrict__ Wx2, const float* __restrict__ bx2,
    const float* __restrict__ bh2,
    float* __restrict__ pre1, float* __restrict__ pre2) {
  int i = blockIdx.x * 256 + threadIdx.x;   // 0 .. 131071
  int dir = i >> 16;                         // uniform per block (blocks 0..255 dir0)
  int j = i & 65535;                         // (t*8+b)*8 + h
  int h = j & 7;
  int tb = j >> 3;
  int idx = x[tb];
  const float* e = emb + (size_t)idx * E;
  const float* Wx = dir ? Wx2 : Wx1;
  float sum = dir ? (bx2[h] + bh2[h]) : (bx1[h] + bh1[h]);
#pragma unroll
  for (int e0 = 0; e0 < E; ++e0) sum = fmaf(e[e0], Wx[e0 * H + h], sum);
  (dir ? pre2 : pre1)[j] = sum;
}

// ---------------------------------------------------------------------------
// Kernel B: the serial recurrences. 1 block, 2 waves (wave = direction).
// lane = b*8+k owns h[b][k]. Emit h BEFORE update (reference semantics).
// pre is software-prefetched 8 steps ahead.
// ---------------------------------------------------------------------------
__global__ __launch_bounds__(128) void rnn_kernel(
    const float* __restrict__ pre1, const float* __restrict__ pre2,
    const float* __restrict__ Wh1, const float* __restrict__ Wh2,
    float* __restrict__ th /* [T*B][16] */) {
  const int tid = threadIdx.x;
  const int dir = tid >> 6;
  const int lane = tid & 63;
  const int b = lane >> 3;
  const int k = lane & 7;
  const float* pre = dir ? pre2 : pre1;
  const float* Wh = dir ? Wh2 : Wh1;

  float w[8];
#pragma unroll
  for (int j = 0; j < 8; ++j) w[j] = Wh[j * H + k];

  float h = 0.f;
  float cur[8], nxt[8];
#pragma unroll
  for (int u = 0; u < 8; ++u) {
    int s = u;
    int tt = dir ? (T - 1 - s) : s;
    cur[u] = pre[tt * 64 + lane];
  }
  for (int blk = 0; blk < T / 8; ++blk) {
    int base = blk * 8;
    if (blk < T / 8 - 1) {
#pragma unroll
      for (int u = 0; u < 8; ++u) {
        int s = base + 8 + u;
        int tt = dir ? (T - 1 - s) : s;
        nxt[u] = pre[tt * 64 + lane];
      }
    }
#pragma unroll
    for (int u = 0; u < 8; ++u) {
      int s = base + u;
      int tt = dir ? (T - 1 - s) : s;
      // emit state BEFORE consuming step tt
      th[(tt * B + b) * (2 * H) + dir * H + k] = h;
      float acc = cur[u];
#pragma unroll
      for (int j = 0; j < 8; ++j) {
        float hj = __shfl(h, (lane & 56) | j, 64);
        acc = fmaf(hj, w[j], acc);
      }
      // sigmoid(acc) = 1 / (1 + exp(-acc))
      h = RCPF(1.0f + EXP2F(acc * -L2E));
    }
#pragma unroll
    for (int u = 0; u < 8; ++u) cur[u] = nxt[u];
  }
}

// ---------------------------------------------------------------------------
// Kernel C: logits = th @ output  then log_softmax over V, written to out.
// 16 rows per block; B-tile (16 x float4) in VGPRs, reused across 16 rows.
// Pass 1: online (max, sum-exp). Block-reduce. Pass 2: recompute + write.
// ---------------------------------------------------------------------------
__global__ __launch_bounds__(256) void logits_kernel(
    const float* __restrict__ th, const float* __restrict__ Wout,
    float* __restrict__ out) {
  const int tid = threadIdx.x;
  const int row0 = blockIdx.x * 16;

  __shared__ float4 th4[16][4];     // 16 rows x 16 coeffs
  __shared__ float red_m[16][4], red_l[16][4];
  __shared__ float sS[16];

  if (tid < 64) {
    th4[tid >> 2][tid & 3] = ((const float4*)th)[row0 * 4 + tid];
  }
  __syncthreads();

  const float4* W4 = (const float4*)Wout;  // [16][8000]

  float m[16], l[16];
#pragma unroll
  for (int r = 0; r < 16; ++r) { m[r] = -INFINITY; l[r] = 0.f; }

  // ---- Pass 1: online max + sum of exp ----
  for (int v4 = tid; v4 < V4; v4 += 256) {
    float4 w[16];
#pragma unroll
    for (int kk = 0; kk < 16; ++kk) w[kk] = W4[(size_t)kk * V4 + v4];
#pragma unroll
    for (int r = 0; r < 16; ++r) {
      float4 c0 = th4[r][0], c1 = th4[r][1], c2 = th4[r][2], c3 = th4[r][3];
      float cc[16] = {c0.x, c0.y, c0.z, c0.w, c1.x, c1.y, c1.z, c1.w,
                      c2.x, c2.y, c2.z, c2.w, c3.x, c3.y, c3.z, c3.w};
      float ax = 0.f, ay = 0.f, az = 0.f, aw = 0.f;
#pragma unroll
      for (int kk = 0; kk < 16; ++kk) {
        ax = fmaf(w[kk].x, cc[kk], ax);
        ay = fmaf(w[kk].y, cc[kk], ay);
        az = fmaf(w[kk].z, cc[kk], az);
        aw = fmaf(w[kk].w, cc[kk], aw);
      }
      float mx = fmaxf(fmaxf(ax, ay), fmaxf(az, aw));
      float nm = fmaxf(m[r], mx);
      float sc = EXP2F((m[r] - nm) * L2E);
      float s = EXP2F((ax - nm) * L2E) + EXP2F((ay - nm) * L2E) +
                EXP2F((az - nm) * L2E) + EXP2F((aw - nm) * L2E);
      l[r] = fmaf(l[r], sc, s);
      m[r] = nm;
    }
  }

  // ---- Block reduction of (m, l) per row ----
  const int wid = tid >> 6, ln = tid & 63;
#pragma unroll
  for (int r = 0; r < 16; ++r) {
    float mm = m[r], ll = l[r];
#pragma unroll
    for (int off = 32; off > 0; off >>= 1) {
      float om = __shfl_xor(mm, off, 64);
      float ol = __shfl_xor(ll, off, 64);
      float nm = fmaxf(mm, om);
      ll = ll * EXP2F((mm - nm) * L2E) + ol * EXP2F((om - nm) * L2E);
      mm = nm;
    }
    if (ln == 0) { red_m[r][wid] = mm; red_l[r][wid] = ll; }
  }
  __syncthreads();
  if (tid < 16) {
    float mm = red_m[tid][0], ll = red_l[tid][0];
#pragma unroll
    for (int i2 = 1; i2 < 4; ++i2) {
      float om = red_m[tid][i2], ol = red_l[tid][i2];
      float nm = fmaxf(mm, om);
      ll = ll * EXP2F((mm - nm) * L2E) + ol * EXP2F((om - nm) * L2E);
      mm = nm;
    }
    sS[tid] = mm + LOG2F(ll) * LN2;  // m + ln(sum exp(. - m))
  }
  __syncthreads();

  // ---- Pass 2: recompute logits, subtract, write ----
  float4* out4 = (float4*)out;
  for (int v4 = tid; v4 < V4; v4 += 256) {
    float4 w[16];
#pragma unroll
    for (int kk = 0; kk < 16; ++kk) w[kk] = W4[(size_t)kk * V4 + v4];
#pragma unroll
    for (int r = 0; r < 16; ++r) {
      float4 c0 = th4[r][0], c1 = th4[r][1], c2 = th4[r][2], c3 = th4[r][3];
      float cc[16] = {c0.x, c0.y, c0.z, c0.w, c1.x, c1.y, c1.z, c1.w,
                      c2.x, c2.y, c2.z, c2.w, c3.x, c3.y, c3.z, c3.w};
      float ax = 0.f, ay = 0.f, az = 0.f, aw = 0.f;
#pragma unroll
      for (int kk = 0; kk < 16; ++kk) {
        ax = fmaf(w[kk].x, cc[kk], ax);
        ay = fmaf(w[kk].y, cc[kk], ay);
        az = fmaf(w[kk].z, cc[kk], az);
        aw = fmaf(w[kk].w, cc[kk], aw);
      }
      float S = sS[r];
      float4 o;
      o.x = ax - S; o.y = ay - S; o.z = az - S; o.w = aw - S;
      out4[(size_t)(row0 + r) * V4 + v4] = o;
    }
  }
}

// ---------------------------------------------------------------------------
extern "C" void kernel_launch(void* const* d_in, const int* in_sizes, int n_in,
                              void* d_out, int out_size, void* d_ws, size_t ws_size,
                              hipStream_t stream) {
  const int* x = (const int*)d_in[0];
  const float* emb = (const float*)d_in[1];
  const float* Wx1 = (const float*)d_in[2];
  const float* bx1 = (const float*)d_in[3];
  const float* Wh1 = (const float*)d_in[4];
  const float* bh1 = (const float*)d_in[5];
  const float* Wx2 = (const float*)d_in[6];
  const float* bx2 = (const float*)d_in[7];
  const float* Wh2 = (const float*)d_in[8];
  const float* bh2 = (const float*)d_in[9];
  const float* Wout = (const float*)d_in[10];
  float* out = (float*)d_out;

  float* ws = (float*)d_ws;
  float* pre1 = ws;                 // T*B*H = 65536 floats
  float* pre2 = ws + TB * H;        // 65536 floats
  float* th = ws + 2 * TB * H;      // T*B*2H = 131072 floats

  proj_kernel<<<512, 256, 0, stream>>>(x, emb, Wx1, bx1, bh1, Wx2, bx2, bh2,
                                       pre1, pre2);
  rnn_kernel<<<1, 128, 0, stream>>>(pre1, pre2, Wh1, Wh2, th);
  logits_kernel<<<TB / 16, 256, 0, stream>>>(th, Wout, out);
}